// Round 4
// baseline (16533.565 us; speedup 1.0000x reference)
//
#include <hip/hip_runtime.h>
#include <stdint.h>
#include <math.h>

typedef _Float16 half8_t __attribute__((ext_vector_type(8)));
typedef float floatx4 __attribute__((ext_vector_type(4)));

#define NN 20000
#define NE 40000
#define NG 1000

// ---- w2(+b2 virtual row) -> fp16 B-fragment chunk images, all 3 layers, one dispatch ----
__global__ __launch_bounds__(256) void prep_all_kernel(
    const float* __restrict__ w2a, const float* __restrict__ b2a, _Float16* __restrict__ oa,
    const float* __restrict__ w2b, const float* __restrict__ b2b, _Float16* __restrict__ ob,
    const float* __restrict__ w2c, const float* __restrict__ b2c, _Float16* __restrict__ oc)
{
  const int TOT0 = 65 * 2 * 64, TOT1 = 129 * 4 * 64, TOT2 = 258 * 4 * 64;
  int idx = blockIdx.x * 256 + threadIdx.x;
  const float *w2, *b2; _Float16* op; int mi, mo, mpsh, CT;
  if (idx < TOT0) { w2 = w2a; b2 = b2a; op = oa; mi = 13; mo = 32; mpsh = 4; CT = 2; }
  else if (idx < TOT0 + TOT1) { idx -= TOT0; w2 = w2b; b2 = b2b; op = ob; mi = 32; mo = 64; mpsh = 5; CT = 4; }
  else if (idx < TOT0 + TOT1 + TOT2) { idx -= TOT0 + TOT1; w2 = w2c; b2 = b2c; op = oc; mi = 64; mo = 64; mpsh = 6; CT = 4; }
  else return;
  int l = idx & 63;
  int ct = (idx >> 6) % CT;
  int c = idx / (64 * CT);
  int q = l >> 4;
  int n = ct * 16 + (l & 15);
  int mask = (1 << mpsh) - 1;
  half8_t v;
#pragma unroll
  for (int j = 0; j < 8; ++j) {
    int r = c * 32 + q * 8 + j;
    int k = r >> mpsh, i = r & mask;
    float f = 0.f;
    if (i < mi) {
      if (k < 128) f = w2[(size_t)(k * mi + i) * mo + n];
      else if (k == 128) f = b2[(size_t)i * mo + n];
    }
    v[j] = (_Float16)f;
  }
  *(half8_t*)(op + (size_t)idx * 8) = v;
}

// ---- layer-0 prep: x (13) -> e16 padded[16] fp16, and xn0 = x@root0 + bias0 ----
__global__ __launch_bounds__(256) void prep0_kernel(
    const float* __restrict__ x, const float* __restrict__ root,
    const float* __restrict__ bias, _Float16* __restrict__ e16,
    float* __restrict__ xn0)
{
  __shared__ float xs[8 * 13];
  int n0 = blockIdx.x * 8;
  int t = threadIdx.x;
  if (t < 104) xs[t] = x[(size_t)n0 * 13 + t];
  __syncthreads();
  if (t < 128) {
    int r = t >> 4, i = t & 15;
    e16[(size_t)(n0 + r) * 16 + i] = (i < 13) ? (_Float16)xs[r * 13 + i] : (_Float16)0.f;
  }
  int r = t >> 5, o = t & 31;
  float acc = bias[o];
#pragma unroll
  for (int i = 0; i < 13; ++i) acc = fmaf(xs[r * 13 + i], root[i * 32 + o], acc);
  xn0[(size_t)(n0 + r) * 32 + o] = acc;
}

// ---- fused: elu(prev conv out) -> e16 for msg, and xnext = elu(x)@root + bias ----
template <int MI, int MOX>
__global__ __launch_bounds__(256) void elu_root_kernel(
    const float* __restrict__ xin, const float* __restrict__ root,
    const float* __restrict__ bias, _Float16* __restrict__ e16,
    float* __restrict__ xnext)
{
  constexpr int R = 256 / MOX;   // 4 rows/block
  __shared__ float es[R * MI];
  int n0 = blockIdx.x * R;
  int t = threadIdx.x;
  for (int idx = t; idx < R * MI; idx += 256) {
    float v = xin[(size_t)n0 * MI + idx];
    v = v > 0.f ? v : (expf(v) - 1.f);
    es[idx] = v;
    e16[(size_t)n0 * MI + idx] = (_Float16)v;
  }
  __syncthreads();
  int r = t / MOX, o = t % MOX;
  float acc = bias[o];
#pragma unroll 8
  for (int i = 0; i < MI; ++i) acc = fmaf(es[r * MI + i], root[i * MOX + o], acc);
  xnext[(size_t)(n0 + r) * MOX + o] = acc;
}

// ---------------- fused h-MLP + message GEMM + scatter-add, barrier-free K-loop ----------------
// C[E,mo] = G[E,129*MIP] @ W ; G[e][k*MIP+i] = h[e][k]*x[e][i] (fp16), h[.][128]=1 carries b2.
// 512 threads = 8 waves; each wave: M=32 edges x N=MO, B-frags stream L2->regs, depth-2
// rotation, no barriers in K-loop. Register budget ~105 (acc 32 + bq 32 + xf <=16 + misc).
template <int MIP, int MO, int NC, int NSPLIT>
__global__ __launch_bounds__(512, 4) void msg4_kernel(
    const float* __restrict__ ea, const float* __restrict__ w1,
    const float* __restrict__ b1, const _Float16* __restrict__ xe,
    const int* __restrict__ src, const int* __restrict__ dst,
    const _Float16* __restrict__ w2h, float* __restrict__ xn)
{
  constexpr int CT = MO / 16;
  constexpr int XLSS = MIP + 8;          // x row stride (halves); row bytes % 16 == 0
  constexpr int HST = 66;                // h row stride (halves): 33 words, conflict-free
  constexpr int SM = (XLSS > HST) ? XLSS : HST;
  constexpr int CHB = CT * 1024;         // bytes per W chunk image
  constexpr int XV = (MIP == 64) ? 2 : 1;
  constexpr int NU = MIP / 8;            // uint4's per x row (2,4,8)

  __shared__ _Float16 sbuf[256 * SM];    // phase A: x rows; phase B: h rows
  __shared__ float w1s[5 * 128 + 128];   // w1 then b1
  __shared__ int dsts[256];

  const int t = threadIdx.x;
  const int wave = t >> 6, lane = t & 63;
  const int l15 = lane & 15, q = lane >> 4;
  const int half = t >> 8;               // 0/1: work-splitting for staging & h
  const int te = t & 255;                // edge slot
  const int split = blockIdx.x % NSPLIT;
  const int e0 = (blockIdx.x / NSPLIT) * 256;

  const int c0 = (NC * split) / NSPLIT;
  const int c1 = (NC * (split + 1)) / NSPLIT;
  const int nc = c1 - c0;
  int kg0, kcnt;
  if constexpr (MIP == 64) { kg0 = c0 >> 1; kcnt = ((c1 - 1) >> 1) - kg0 + 1; }
  else if constexpr (MIP == 32) { kg0 = c0; kcnt = nc; }
  else { kg0 = 2 * c0; kcnt = 2 * nc; }

  // ---- phase A: stage x rows (split halves), w1/b1, dst; edge attrs to regs ----
  int eg = e0 + te; if (eg >= NE) eg = NE - 1;
  if (half == 0) dsts[te] = dst[eg];
  float ear[5];
#pragma unroll
  for (int j = 0; j < 5; ++j) ear[j] = ea[(size_t)eg * 5 + j];
  {
    const uint4* xr = (const uint4*)(xe + (size_t)src[eg] * MIP);
    uint4* xd = (uint4*)(sbuf + te * XLSS);
#pragma unroll
    for (int u = half * (NU / 2); u < (half + 1) * (NU / 2); ++u) xd[u] = xr[u];
  }
  for (int i = t; i < 768; i += 512) w1s[i] = (i < 640) ? w1[i] : b1[i - 640];
  __syncthreads();

  // ---- x fragments to registers (2 M-subtiles per wave) ----
  const int wbase = wave * 32;
  half8_t xf[2][XV];
#pragma unroll
  for (int s = 0; s < 2; ++s) {
    int el = wbase + s * 16 + l15;
    int i0 = (MIP == 16) ? (q & 1) * 8 : q * 8;
    xf[s][0] = *(const half8_t*)(sbuf + el * XLSS + i0);
    if constexpr (MIP == 64)
      xf[s][XV - 1] = *(const half8_t*)(sbuf + el * XLSS + 32 + q * 8);
  }
  __syncthreads();

  // ---- phase B: h rows into sbuf (each edge split across thread halves) ----
  {
    int kh = (kcnt + 1) >> 1;
    int klo = half * kh;
    int khi = klo + kh; if (khi > kcnt) khi = kcnt;
    for (int kl = klo; kl < khi; ++kl) {
      int kg = kg0 + kl;
      float v;
      if (kg < 128) {
        v = w1s[640 + kg];
#pragma unroll
        for (int j = 0; j < 5; ++j) v = fmaf(ear[j], w1s[j * 128 + kg], v);
        v = fmaxf(v, 0.f);
      } else v = (kg == 128) ? 1.f : 0.f;
      sbuf[te * HST + kl] = (_Float16)v;
    }
  }
  __syncthreads();

  // ---- barrier-free K loop ----
  floatx4 acc[2][CT];
#pragma unroll
  for (int s = 0; s < 2; ++s)
#pragma unroll
    for (int b = 0; b < CT; ++b) acc[s][b] = (floatx4){0.f, 0.f, 0.f, 0.f};

  const char* wg = (const char*)w2h + (size_t)lane * 16;
  half8_t bq[2][CT];
#pragma unroll
  for (int b = 0; b < CT; ++b) {
    bq[0][b] = *(const half8_t*)(wg + (size_t)c0 * CHB + b * 1024);
    bq[1][b] = *(const half8_t*)(wg + (size_t)(c0 + 1) * CHB + b * 1024);
  }

#pragma unroll 2
  for (int cc = 0; cc < nc; ++cc) {
    const int c = c0 + cc;
    int kl;
    if constexpr (MIP == 64) kl = (c >> 1) - kg0;
    else if constexpr (MIP == 32) kl = cc;
    else kl = 2 * cc + (q >> 1);
#pragma unroll
    for (int s = 0; s < 2; ++s) {
      _Float16 hv = sbuf[(wbase + s * 16 + l15) * HST + kl];
      half8_t af;
      if constexpr (MIP == 64) af = xf[s][c & 1] * hv;
      else af = xf[s][0] * hv;
#pragma unroll
      for (int b = 0; b < CT; ++b)
        acc[s][b] = __builtin_amdgcn_mfma_f32_16x16x32_f16(af, bq[cc & 1][b], acc[s][b], 0, 0, 0);
    }
    int cp = c + 2; if (cp > c1 - 1) cp = c1 - 1;
#pragma unroll
    for (int b = 0; b < CT; ++b)
      bq[cc & 1][b] = *(const half8_t*)(wg + (size_t)cp * CHB + b * 1024);
  }

  // ---- epilogue: D row = 4q+r (within 16-tile), col = l15; scatter-add ----
#pragma unroll
  for (int s = 0; s < 2; ++s) {
    int rowb = wbase + s * 16 + q * 4;
#pragma unroll
    for (int b = 0; b < CT; ++b) {
      int n = b * 16 + l15;
#pragma unroll
      for (int r = 0; r < 4; ++r) {
        int row = rowb + r;
        if (e0 + row < NE)
          atomicAdd(&xn[(size_t)dsts[row] * MO + n], acc[s][b][r]);
      }
    }
  }
}

// ---- pooling (segment mean over sorted batch, fused ELU) + 3-layer FC head ----
__global__ __launch_bounds__(64) void pool_fc_kernel(
    const float* __restrict__ xn2, const int* __restrict__ batch,
    const float* __restrict__ f1w, const float* __restrict__ f1b,
    const float* __restrict__ f2w, const float* __restrict__ f2b,
    const float* __restrict__ f3w, const float* __restrict__ f3b,
    float* __restrict__ out)
{
  __shared__ float xg[64]; __shared__ float a1[32]; __shared__ float a2[16];
  int g = blockIdx.x, t = threadIdx.x;
  int lo = 0, hi = NN;
  while (lo < hi) { int m = (lo + hi) >> 1; if (batch[m] < g) lo = m + 1; else hi = m; }
  int start = lo; hi = NN;
  while (lo < hi) { int m = (lo + hi) >> 1; if (batch[m] <= g) lo = m + 1; else hi = m; }
  int end = lo;
  float acc = 0.f;
  for (int n = start; n < end; ++n) {
    float v = xn2[(size_t)n * 64 + t];
    acc += v > 0.f ? v : (expf(v) - 1.f);
  }
  float c = (end > start) ? (float)(end - start) : 1.f;
  xg[t] = acc / c;
  __syncthreads();
  if (t < 32) {
    float a = f1b[t];
    for (int i = 0; i < 64; ++i) a = fmaf(xg[i], f1w[i * 32 + t], a);
    a1[t] = a > 0.f ? a : (expf(a) - 1.f);
  }
  __syncthreads();
  if (t < 16) {
    float a = f2b[t];
    for (int i = 0; i < 32; ++i) a = fmaf(a1[i], f2w[i * 16 + t], a);
    a2[t] = a > 0.f ? a : (expf(a) - 1.f);
  }
  __syncthreads();
  if (t == 0) {
    float a = f3b[0];
    for (int i = 0; i < 16; ++i) a = fmaf(a2[i], f3w[i], a);
    out[g] = a;
  }
}

extern "C" void kernel_launch(void* const* d_in, const int* in_sizes, int n_in,
                              void* d_out, int out_size, void* d_ws, size_t ws_size,
                              hipStream_t stream)
{
  const float* x_in  = (const float*)d_in[0];
  const int*   ei    = (const int*)d_in[1];
  const float* ea    = (const float*)d_in[2];
  const int*   batch = (const int*)d_in[3];
  const float* W1[3] = {(const float*)d_in[4],  (const float*)d_in[10], (const float*)d_in[16]};
  const float* B1[3] = {(const float*)d_in[5],  (const float*)d_in[11], (const float*)d_in[17]};
  const float* W2[3] = {(const float*)d_in[6],  (const float*)d_in[12], (const float*)d_in[18]};
  const float* B2[3] = {(const float*)d_in[7],  (const float*)d_in[13], (const float*)d_in[19]};
  const float* RT[3] = {(const float*)d_in[8],  (const float*)d_in[14], (const float*)d_in[20]};
  const float* BS[3] = {(const float*)d_in[9],  (const float*)d_in[15], (const float*)d_in[21]};
  const float* f1w = (const float*)d_in[22]; const float* f1b = (const float*)d_in[23];
  const float* f2w = (const float*)d_in[24]; const float* f2b = (const float*)d_in[25];
  const float* f3w = (const float*)d_in[26]; const float* f3b = (const float*)d_in[27];

  char* ws = (char*)d_ws;
  size_t off = 0;
  auto alloc = [&](size_t bytes) { void* p = ws + off; off += (bytes + 255) & ~(size_t)255; return p; };
  float*    xn0   = (float*)alloc((size_t)NN * 32 * 4);
  float*    xn1   = (float*)alloc((size_t)NN * 64 * 4);
  float*    xn2   = (float*)alloc((size_t)NN * 64 * 4);
  _Float16* e16_0 = (_Float16*)alloc((size_t)NN * 16 * 2);
  _Float16* e16_1 = (_Float16*)alloc((size_t)NN * 32 * 2);
  _Float16* e16_2 = (_Float16*)alloc((size_t)NN * 64 * 2);
  _Float16* w2h0  = (_Float16*)alloc((size_t)65 * 2048);
  _Float16* w2h1  = (_Float16*)alloc((size_t)129 * 4096);
  _Float16* w2h2  = (_Float16*)alloc((size_t)258 * 4096);

  const int* srcp = ei;
  const int* dstp = ei + NE;
  const int NBLK = (NE + 255) / 256;   // 157

  prep_all_kernel<<<(65*2*64 + 129*4*64 + 258*4*64 + 255) / 256, 256, 0, stream>>>(
      W2[0], B2[0], w2h0, W2[1], B2[1], w2h1, W2[2], B2[2], w2h2);
  prep0_kernel<<<NN / 8, 256, 0, stream>>>(x_in, RT[0], BS[0], e16_0, xn0);

  msg4_kernel<16, 32, 65, 3><<<NBLK * 3, 512, 0, stream>>>(
      ea, W1[0], B1[0], e16_0, srcp, dstp, w2h0, xn0);
  elu_root_kernel<32, 64><<<NN / 4, 256, 0, stream>>>(xn0, RT[1], BS[1], e16_1, xn1);

  msg4_kernel<32, 64, 129, 4><<<NBLK * 4, 512, 0, stream>>>(
      ea, W1[1], B1[1], e16_1, srcp, dstp, w2h1, xn1);
  elu_root_kernel<64, 64><<<NN / 4, 256, 0, stream>>>(xn1, RT[2], BS[2], e16_2, xn2);

  msg4_kernel<64, 64, 258, 4><<<NBLK * 4, 512, 0, stream>>>(
      ea, W1[2], B1[2], e16_2, srcp, dstp, w2h2, xn2);

  pool_fc_kernel<<<NG, 64, 0, stream>>>(xn2, batch, f1w, f1b, f2w, f2b, f3w, f3b, (float*)d_out);
}

// Round 5
// 319.079 us; speedup vs baseline: 51.8165x; 51.8165x over previous
//
#include <hip/hip_runtime.h>
#include <stdint.h>
#include <math.h>

typedef _Float16 half8_t __attribute__((ext_vector_type(8)));
typedef float floatx4 __attribute__((ext_vector_type(4)));

#define NN 20000
#define NE 40000
#define NG 1000
#define NBLK 157      // (NE+255)/256
#define NSPLIT 4

// ---- w2(+b2 virtual row) -> fp16 B-fragment chunk images (K padded), all 3 layers ----
__global__ __launch_bounds__(256) void prep_all_kernel(
    const float* __restrict__ w2a, const float* __restrict__ b2a, _Float16* __restrict__ oa,
    const float* __restrict__ w2b, const float* __restrict__ b2b, _Float16* __restrict__ ob,
    const float* __restrict__ w2c, const float* __restrict__ b2c, _Float16* __restrict__ oc)
{
  const int TOT0 = 68 * 2 * 64, TOT1 = 132 * 4 * 64, TOT2 = 264 * 4 * 64;
  int idx = blockIdx.x * 256 + threadIdx.x;
  const float *w2, *b2; _Float16* op; int mi, mo, mpsh, CT;
  if (idx < TOT0) { w2 = w2a; b2 = b2a; op = oa; mi = 13; mo = 32; mpsh = 4; CT = 2; }
  else if (idx < TOT0 + TOT1) { idx -= TOT0; w2 = w2b; b2 = b2b; op = ob; mi = 32; mo = 64; mpsh = 5; CT = 4; }
  else if (idx < TOT0 + TOT1 + TOT2) { idx -= TOT0 + TOT1; w2 = w2c; b2 = b2c; op = oc; mi = 64; mo = 64; mpsh = 6; CT = 4; }
  else return;
  int l = idx & 63;
  int ct = (idx >> 6) % CT;
  int c = idx / (64 * CT);
  int q = l >> 4;
  int n = ct * 16 + (l & 15);
  int mask = (1 << mpsh) - 1;
  half8_t v;
#pragma unroll
  for (int j = 0; j < 8; ++j) {
    int r = c * 32 + q * 8 + j;
    int k = r >> mpsh, i = r & mask;
    float f = 0.f;
    if (i < mi) {
      if (k < 128) f = w2[(size_t)(k * mi + i) * mo + n];
      else if (k == 128) f = b2[(size_t)i * mo + n];
    }
    v[j] = (_Float16)f;
  }
  *(half8_t*)(op + (size_t)idx * 8) = v;
}

// ---- layer-0 prep: x (13) -> e16 padded[16] fp16, and xn0 = x@root0 + bias0 ----
__global__ __launch_bounds__(256) void prep0_kernel(
    const float* __restrict__ x, const float* __restrict__ root,
    const float* __restrict__ bias, _Float16* __restrict__ e16,
    float* __restrict__ xn0)
{
  __shared__ float xs[8 * 13];
  int n0 = blockIdx.x * 8;
  int t = threadIdx.x;
  if (t < 104) xs[t] = x[(size_t)n0 * 13 + t];
  __syncthreads();
  if (t < 128) {
    int r = t >> 4, i = t & 15;
    e16[(size_t)(n0 + r) * 16 + i] = (i < 13) ? (_Float16)xs[r * 13 + i] : (_Float16)0.f;
  }
  int r = t >> 5, o = t & 31;
  float acc = bias[o];
#pragma unroll
  for (int i = 0; i < 13; ++i) acc = fmaf(xs[r * 13 + i], root[i * 32 + o], acc);
  xn0[(size_t)(n0 + r) * 32 + o] = acc;
}

// ---- fused: elu(prev conv out) -> e16 for msg, and xnext = elu(x)@root + bias ----
template <int MI, int MOX>
__global__ __launch_bounds__(256) void elu_root_kernel(
    const float* __restrict__ xin, const float* __restrict__ root,
    const float* __restrict__ bias, _Float16* __restrict__ e16,
    float* __restrict__ xnext)
{
  constexpr int R = 256 / MOX;   // 4 rows/block
  __shared__ float es[R * MI];
  int n0 = blockIdx.x * R;
  int t = threadIdx.x;
  for (int idx = t; idx < R * MI; idx += 256) {
    float v = xin[(size_t)n0 * MI + idx];
    v = v > 0.f ? v : (expf(v) - 1.f);
    es[idx] = v;
    e16[(size_t)n0 * MI + idx] = (_Float16)v;
  }
  __syncthreads();
  int r = t / MOX, o = t % MOX;
  float acc = bias[o];
#pragma unroll 8
  for (int i = 0; i < MI; ++i) acc = fmaf(es[r * MI + i], root[i * MOX + o], acc);
  xnext[(size_t)(n0 + r) * MOX + o] = acc;
}

// ---------------- fused h-MLP + message GEMM + scatter-add ----------------
// C[E,MO] = G[E,Kpad] @ W ; G[e][k*MIP+i] = h[e][k]*x[e][i] (fp16), h[.][128]=1 carries b2,
// K padded so NCC = chunks/split is constexpr (all register-array indices static).
// 256 thr = 4 waves, block = 256 edges, wave = M64 x N=MO. W chunk double-buffered in LDS,
// one barrier per chunk; x frags in regs; grid = NBLK*NSPLIT = 628.
template <int MIP, int MO, int NCC, int KCNT>
__global__ __launch_bounds__(256, 2) void msg5_kernel(
    const float* __restrict__ ea, const float* __restrict__ w1,
    const float* __restrict__ b1, const _Float16* __restrict__ xe,
    const int* __restrict__ src, const int* __restrict__ dst,
    const _Float16* __restrict__ w2h, float* __restrict__ xn)
{
  constexpr int CT = MO / 16;            // c-tiles per chunk (full N per wave)
  constexpr int CHB = CT * 1024;         // bytes per W chunk image
  constexpr int XLSS = MIP + 8;          // x row stride (halves)
  constexpr int HST = 66;                // h row stride (halves) = 33 words, conflict-free
  constexpr int SM = (XLSS > HST) ? XLSS : HST;
  constexpr int XV = (MIP == 64) ? 2 : 1;
  constexpr int NU = MIP / 8;            // uint4s per x row

  __shared__ _Float16 sbuf[256 * SM];    // phase A: x rows; phase B: h rows
  __shared__ uint4 wsb[2][CT * 64];      // double-buffered W chunk
  __shared__ float w1s[5 * 128 + 128];   // w1 then b1
  __shared__ int dsts[256];

  const int t = threadIdx.x;
  const int wave = t >> 6, lane = t & 63;
  const int l15 = lane & 15, q = lane >> 4;
  const int split = blockIdx.x / NBLK;
  const int eblk = blockIdx.x % NBLK;
  const int e0 = eblk * 256;
  const int c0 = NCC * split;            // even (NCC even for MIP==64)
  const int kg0 = KCNT * split;

  // ---- phase A: stage x rows, w1/b1, dst; edge attrs to regs ----
  int eg = e0 + t; if (eg >= NE) eg = NE - 1;
  dsts[t] = dst[eg];
  float ear[5];
#pragma unroll
  for (int j = 0; j < 5; ++j) ear[j] = ea[(size_t)eg * 5 + j];
  {
    const uint4* xr = (const uint4*)(xe + (size_t)src[eg] * MIP);
    uint4* xd = (uint4*)(sbuf + t * XLSS);
#pragma unroll
    for (int u = 0; u < NU; ++u) xd[u] = xr[u];
  }
  for (int i = t; i < 768; i += 256) w1s[i] = (i < 640) ? w1[i] : b1[i - 640];
  __syncthreads();

  // ---- x fragments to registers (4 M-subtiles per wave) ----
  const int wbase = wave * 64;
  half8_t xf[4][XV];
#pragma unroll
  for (int s = 0; s < 4; ++s) {
    int el = wbase + s * 16 + l15;
    int i0 = (MIP == 16) ? (q & 1) * 8 : q * 8;
    xf[s][0] = *(const half8_t*)(sbuf + el * XLSS + i0);
    if constexpr (MIP == 64)
      xf[s][XV - 1] = *(const half8_t*)(sbuf + el * XLSS + 32 + q * 8);
  }
  __syncthreads();

  // ---- phase B: h row for this thread's edge (overwrites x staging) ----
#pragma unroll 4
  for (int kl = 0; kl < KCNT; ++kl) {
    int kg = kg0 + kl;
    float v;
    if (kg < 128) {
      v = w1s[640 + kg];
#pragma unroll
      for (int j = 0; j < 5; ++j) v = fmaf(ear[j], w1s[j * 128 + kg], v);
      v = fmaxf(v, 0.f);
    } else v = (kg == 128) ? 1.f : 0.f;
    sbuf[t * HST + kl] = (_Float16)v;
  }
  __syncthreads();

  // ---- K loop: one barrier per chunk, double-buffered LDS W, all indices static ----
  floatx4 acc[4][CT];
#pragma unroll
  for (int s = 0; s < 4; ++s)
#pragma unroll
    for (int b = 0; b < CT; ++b) acc[s][b] = (floatx4){0.f, 0.f, 0.f, 0.f};

  const char* wgp = (const char*)w2h + (size_t)c0 * CHB;
  uint4 r4; uint2 r2;
  if constexpr (CT == 4) r4 = *(const uint4*)(wgp + t * 16);
  else r2 = *(const uint2*)(wgp + t * 8);

#pragma unroll 2
  for (int cc = 0; cc < NCC; ++cc) {
    if constexpr (CT == 4) wsb[cc & 1][t] = r4;
    else ((uint2*)wsb[cc & 1])[t] = r2;
    __syncthreads();
    if (cc + 1 < NCC) {
      if constexpr (CT == 4) r4 = *(const uint4*)(wgp + (size_t)(cc + 1) * CHB + t * 16);
      else r2 = *(const uint2*)(wgp + (size_t)(cc + 1) * CHB + t * 8);
    }
    const _Float16* wb = (const _Float16*)wsb[cc & 1];
    half8_t bf[CT];
#pragma unroll
    for (int b = 0; b < CT; ++b)
      bf[b] = *(const half8_t*)(wb + (b * 64 + lane) * 8);
    int kl;
    if constexpr (MIP == 64) kl = cc >> 1;
    else if constexpr (MIP == 32) kl = cc;
    else kl = 2 * cc + (q >> 1);
#pragma unroll
    for (int s = 0; s < 4; ++s) {
      _Float16 hv = sbuf[(wbase + s * 16 + l15) * HST + kl];
      half8_t af;
      if constexpr (MIP == 64) af = xf[s][cc & 1] * hv;   // c0 even -> static parity
      else af = xf[s][0] * hv;
#pragma unroll
      for (int b = 0; b < CT; ++b)
        acc[s][b] = __builtin_amdgcn_mfma_f32_16x16x32_f16(af, bf[b], acc[s][b], 0, 0, 0);
    }
  }

  // ---- epilogue: D row = 4q+r (within 16-tile), col = l15; scatter-add ----
#pragma unroll
  for (int s = 0; s < 4; ++s) {
    int rowb = wbase + s * 16 + q * 4;
#pragma unroll
    for (int b = 0; b < CT; ++b) {
      int n = b * 16 + l15;
#pragma unroll
      for (int r = 0; r < 4; ++r) {
        int row = rowb + r;
        if (e0 + row < NE)
          atomicAdd(&xn[(size_t)dsts[row] * MO + n], acc[s][b][r]);
      }
    }
  }
}

// ---- pooling (segment mean over sorted batch, fused ELU) + 3-layer FC head ----
__global__ __launch_bounds__(64) void pool_fc_kernel(
    const float* __restrict__ xn2, const int* __restrict__ batch,
    const float* __restrict__ f1w, const float* __restrict__ f1b,
    const float* __restrict__ f2w, const float* __restrict__ f2b,
    const float* __restrict__ f3w, const float* __restrict__ f3b,
    float* __restrict__ out)
{
  __shared__ float xg[64]; __shared__ float a1[32]; __shared__ float a2[16];
  int g = blockIdx.x, t = threadIdx.x;
  int lo = 0, hi = NN;
  while (lo < hi) { int m = (lo + hi) >> 1; if (batch[m] < g) lo = m + 1; else hi = m; }
  int start = lo; hi = NN;
  while (lo < hi) { int m = (lo + hi) >> 1; if (batch[m] <= g) lo = m + 1; else hi = m; }
  int end = lo;
  float acc = 0.f;
  for (int n = start; n < end; ++n) {
    float v = xn2[(size_t)n * 64 + t];
    acc += v > 0.f ? v : (expf(v) - 1.f);
  }
  float c = (end > start) ? (float)(end - start) : 1.f;
  xg[t] = acc / c;
  __syncthreads();
  if (t < 32) {
    float a = f1b[t];
    for (int i = 0; i < 64; ++i) a = fmaf(xg[i], f1w[i * 32 + t], a);
    a1[t] = a > 0.f ? a : (expf(a) - 1.f);
  }
  __syncthreads();
  if (t < 16) {
    float a = f2b[t];
    for (int i = 0; i < 32; ++i) a = fmaf(a1[i], f2w[i * 16 + t], a);
    a2[t] = a > 0.f ? a : (expf(a) - 1.f);
  }
  __syncthreads();
  if (t == 0) {
    float a = f3b[0];
    for (int i = 0; i < 16; ++i) a = fmaf(a2[i], f3w[i], a);
    out[g] = a;
  }
}

extern "C" void kernel_launch(void* const* d_in, const int* in_sizes, int n_in,
                              void* d_out, int out_size, void* d_ws, size_t ws_size,
                              hipStream_t stream)
{
  const float* x_in  = (const float*)d_in[0];
  const int*   ei    = (const int*)d_in[1];
  const float* ea    = (const float*)d_in[2];
  const int*   batch = (const int*)d_in[3];
  const float* W1[3] = {(const float*)d_in[4],  (const float*)d_in[10], (const float*)d_in[16]};
  const float* B1[3] = {(const float*)d_in[5],  (const float*)d_in[11], (const float*)d_in[17]};
  const float* W2[3] = {(const float*)d_in[6],  (const float*)d_in[12], (const float*)d_in[18]};
  const float* B2[3] = {(const float*)d_in[7],  (const float*)d_in[13], (const float*)d_in[19]};
  const float* RT[3] = {(const float*)d_in[8],  (const float*)d_in[14], (const float*)d_in[20]};
  const float* BS[3] = {(const float*)d_in[9],  (const float*)d_in[15], (const float*)d_in[21]};
  const float* f1w = (const float*)d_in[22]; const float* f1b = (const float*)d_in[23];
  const float* f2w = (const float*)d_in[24]; const float* f2b = (const float*)d_in[25];
  const float* f3w = (const float*)d_in[26]; const float* f3b = (const float*)d_in[27];

  char* ws = (char*)d_ws;
  size_t off = 0;
  auto alloc = [&](size_t bytes) { void* p = ws + off; off += (bytes + 255) & ~(size_t)255; return p; };
  float*    xn0   = (float*)alloc((size_t)NN * 32 * 4);
  float*    xn1   = (float*)alloc((size_t)NN * 64 * 4);
  float*    xn2   = (float*)alloc((size_t)NN * 64 * 4);
  _Float16* e16_0 = (_Float16*)alloc((size_t)NN * 16 * 2);
  _Float16* e16_1 = (_Float16*)alloc((size_t)NN * 32 * 2);
  _Float16* e16_2 = (_Float16*)alloc((size_t)NN * 64 * 2);
  _Float16* w2h0  = (_Float16*)alloc((size_t)68 * 2048);
  _Float16* w2h1  = (_Float16*)alloc((size_t)132 * 4096);
  _Float16* w2h2  = (_Float16*)alloc((size_t)264 * 4096);

  const int* srcp = ei;
  const int* dstp = ei + NE;

  prep_all_kernel<<<(68*2*64 + 132*4*64 + 264*4*64 + 255) / 256, 256, 0, stream>>>(
      W2[0], B2[0], w2h0, W2[1], B2[1], w2h1, W2[2], B2[2], w2h2);
  prep0_kernel<<<NN / 8, 256, 0, stream>>>(x_in, RT[0], BS[0], e16_0, xn0);

  msg5_kernel<16, 32, 17, 34><<<NBLK * NSPLIT, 256, 0, stream>>>(
      ea, W1[0], B1[0], e16_0, srcp, dstp, w2h0, xn0);
  elu_root_kernel<32, 64><<<NN / 4, 256, 0, stream>>>(xn0, RT[1], BS[1], e16_1, xn1);

  msg5_kernel<32, 64, 33, 33><<<NBLK * NSPLIT, 256, 0, stream>>>(
      ea, W1[1], B1[1], e16_1, srcp, dstp, w2h1, xn1);
  elu_root_kernel<64, 64><<<NN / 4, 256, 0, stream>>>(xn1, RT[2], BS[2], e16_2, xn2);

  msg5_kernel<64, 64, 66, 33><<<NBLK * NSPLIT, 256, 0, stream>>>(
      ea, W1[2], B1[2], e16_2, srcp, dstp, w2h2, xn2);

  pool_fc_kernel<<<NG, 64, 0, stream>>>(xn2, batch, f1w, f1b, f2w, f2b, f3w, f3b, (float*)d_out);
}

// Round 6
// 313.763 us; speedup vs baseline: 52.6945x; 1.0169x over previous
//
#include <hip/hip_runtime.h>
#include <stdint.h>
#include <math.h>

typedef _Float16 half8_t __attribute__((ext_vector_type(8)));
typedef float floatx4 __attribute__((ext_vector_type(4)));

#define NN 20000
#define NE 40000
#define NG 1000
#define NBLK 157      // (NE+255)/256
#define NSPLIT 4

// ---- w2(+b2 virtual row) -> fp16 B-fragment chunk images (K padded), all 3 layers ----
__global__ __launch_bounds__(256) void prep_all_kernel(
    const float* __restrict__ w2a, const float* __restrict__ b2a, _Float16* __restrict__ oa,
    const float* __restrict__ w2b, const float* __restrict__ b2b, _Float16* __restrict__ ob,
    const float* __restrict__ w2c, const float* __restrict__ b2c, _Float16* __restrict__ oc)
{
  const int TOT0 = 72 * 2 * 64, TOT1 = 132 * 4 * 64, TOT2 = 264 * 4 * 64;
  int idx = blockIdx.x * 256 + threadIdx.x;
  const float *w2, *b2; _Float16* op; int mi, mo, mpsh, CT;
  if (idx < TOT0) { w2 = w2a; b2 = b2a; op = oa; mi = 13; mo = 32; mpsh = 4; CT = 2; }
  else if (idx < TOT0 + TOT1) { idx -= TOT0; w2 = w2b; b2 = b2b; op = ob; mi = 32; mo = 64; mpsh = 5; CT = 4; }
  else if (idx < TOT0 + TOT1 + TOT2) { idx -= TOT0 + TOT1; w2 = w2c; b2 = b2c; op = oc; mi = 64; mo = 64; mpsh = 6; CT = 4; }
  else return;
  int l = idx & 63;
  int ct = (idx >> 6) % CT;
  int c = idx / (64 * CT);
  int q = l >> 4;
  int n = ct * 16 + (l & 15);
  int mask = (1 << mpsh) - 1;
  half8_t v;
#pragma unroll
  for (int j = 0; j < 8; ++j) {
    int r = c * 32 + q * 8 + j;
    int k = r >> mpsh, i = r & mask;
    float f = 0.f;
    if (i < mi) {
      if (k < 128) f = w2[(size_t)(k * mi + i) * mo + n];
      else if (k == 128) f = b2[(size_t)i * mo + n];
    }
    v[j] = (_Float16)f;
  }
  *(half8_t*)(op + (size_t)idx * 8) = v;
}

// ---- layer-0 prep: x (13) -> e16 padded[16] fp16, and xn0 = x@root0 + bias0 ----
__global__ __launch_bounds__(256) void prep0_kernel(
    const float* __restrict__ x, const float* __restrict__ root,
    const float* __restrict__ bias, _Float16* __restrict__ e16,
    float* __restrict__ xn0)
{
  __shared__ float xs[8 * 13];
  int n0 = blockIdx.x * 8;
  int t = threadIdx.x;
  if (t < 104) xs[t] = x[(size_t)n0 * 13 + t];
  __syncthreads();
  if (t < 128) {
    int r = t >> 4, i = t & 15;
    e16[(size_t)(n0 + r) * 16 + i] = (i < 13) ? (_Float16)xs[r * 13 + i] : (_Float16)0.f;
  }
  int r = t >> 5, o = t & 31;
  float acc = bias[o];
#pragma unroll
  for (int i = 0; i < 13; ++i) acc = fmaf(xs[r * 13 + i], root[i * 32 + o], acc);
  xn0[(size_t)(n0 + r) * 32 + o] = acc;
}

// ---- fused: elu(prev conv out) -> e16 for msg, and xnext = elu(x)@root + bias ----
template <int MI, int MOX>
__global__ __launch_bounds__(256) void elu_root_kernel(
    const float* __restrict__ xin, const float* __restrict__ root,
    const float* __restrict__ bias, _Float16* __restrict__ e16,
    float* __restrict__ xnext)
{
  constexpr int R = 256 / MOX;   // 4 rows/block
  __shared__ float es[R * MI];
  int n0 = blockIdx.x * R;
  int t = threadIdx.x;
  for (int idx = t; idx < R * MI; idx += 256) {
    float v = xin[(size_t)n0 * MI + idx];
    v = v > 0.f ? v : (expf(v) - 1.f);
    es[idx] = v;
    e16[(size_t)n0 * MI + idx] = (_Float16)v;
  }
  __syncthreads();
  int r = t / MOX, o = t % MOX;
  float acc = bias[o];
#pragma unroll 8
  for (int i = 0; i < MI; ++i) acc = fmaf(es[r * MI + i], root[i * MOX + o], acc);
  xnext[(size_t)(n0 + r) * MOX + o] = acc;
}

// ---------------- fused h-MLP + message GEMM + scatter-add, barrier-free K-loop ----------------
// C[E,MO] = G[E,Kpad] @ W ; G[e][k*MIP+i] = h[e][k]*x[e][i] (fp16), h[.][128]=1 carries b2.
// 256 thr = 4 waves; wave = M64 edges x N=MO over its K-split. B-frags stream L2->regs with a
// depth-3 rotation bq[3][CT]; macro-iter of MAC chunks so slot (j%3) and xf parity (j&1) are
// compile-time (NO dynamic register indexing). Zero barriers in the K-loop.
template <int MIP, int MO, int NCC, int KCNT>
__global__ __launch_bounds__(256, 2) void msg6_kernel(
    const float* __restrict__ ea, const float* __restrict__ w1,
    const float* __restrict__ b1, const _Float16* __restrict__ xe,
    const int* __restrict__ src, const int* __restrict__ dst,
    const _Float16* __restrict__ w2h, float* __restrict__ xn)
{
  constexpr int CT = MO / 16;            // 16-col tiles per chunk
  constexpr int CHB = CT * 1024;         // bytes per W chunk image
  constexpr int XLSS = MIP + 8;          // x staging row stride (halves)
  constexpr int HST = (KCNT + 2) & ~1;   // h row stride (halves); word-stride odd -> conflict-free
  constexpr int SM = (XLSS > HST) ? XLSS : HST;
  constexpr int XV = (MIP == 64) ? 2 : 1;
  constexpr int NU = MIP / 8;            // uint4s per x row
  constexpr int MAC = (MIP == 64) ? 6 : 3;   // chunks per macro-iter (parity-uniform)
  constexpr int NMAC = NCC / MAC;

  __shared__ _Float16 sbuf[256 * SM];    // phase A: x rows; phase B: h rows
  __shared__ float w1s[5 * 128 + 128];   // w1 then b1
  __shared__ int dsts[256];

  const int t = threadIdx.x;
  const int wave = t >> 6, lane = t & 63;
  const int l15 = lane & 15, q = lane >> 4;
  const int split = blockIdx.x / NBLK;
  const int eblk = blockIdx.x % NBLK;
  const int e0 = eblk * 256;
  const int c0 = NCC * split;            // even for all layers used
  const int kg0 = KCNT * split;

  // ---- phase A: stage x rows, w1/b1, dst; edge attrs to regs ----
  int eg = e0 + t; if (eg >= NE) eg = NE - 1;
  dsts[t] = dst[eg];
  float ear[5];
#pragma unroll
  for (int j = 0; j < 5; ++j) ear[j] = ea[(size_t)eg * 5 + j];
  {
    const uint4* xr = (const uint4*)(xe + (size_t)src[eg] * MIP);
    uint4* xd = (uint4*)(sbuf + t * XLSS);
#pragma unroll
    for (int u = 0; u < NU; ++u) xd[u] = xr[u];
  }
  for (int i = t; i < 768; i += 256) w1s[i] = (i < 640) ? w1[i] : b1[i - 640];
  __syncthreads();

  // ---- x fragments to registers (4 M-subtiles per wave) ----
  const int wbase = wave * 64;
  half8_t xf[4][XV];
#pragma unroll
  for (int s = 0; s < 4; ++s) {
    int el = wbase + s * 16 + l15;
    int i0 = (MIP == 16) ? (q & 1) * 8 : q * 8;
    xf[s][0] = *(const half8_t*)(sbuf + el * XLSS + i0);
    if constexpr (MIP == 64)
      xf[s][XV - 1] = *(const half8_t*)(sbuf + el * XLSS + 32 + q * 8);
  }
  __syncthreads();

  // ---- phase B: h row for this thread's edge (overwrites x staging) ----
#pragma unroll 4
  for (int kl = 0; kl < KCNT; ++kl) {
    int kg = kg0 + kl;
    float v;
    if (kg < 128) {
      v = w1s[640 + kg];
#pragma unroll
      for (int j = 0; j < 5; ++j) v = fmaf(ear[j], w1s[j * 128 + kg], v);
      v = fmaxf(v, 0.f);
    } else v = (kg == 128) ? 1.f : 0.f;
    sbuf[t * HST + kl] = (_Float16)v;
  }
  __syncthreads();   // last barrier — K-loop below is barrier-free

  // ---- barrier-free K loop: L2 -> regs, depth-3 rotation, all reg indices static ----
  floatx4 acc[4][CT];
#pragma unroll
  for (int s = 0; s < 4; ++s)
#pragma unroll
    for (int b = 0; b < CT; ++b) acc[s][b] = (floatx4){0.f, 0.f, 0.f, 0.f};

  const char* wgp = (const char*)w2h + (size_t)c0 * CHB + (size_t)lane * 16;
  half8_t bq[3][CT];
#pragma unroll
  for (int p = 0; p < 3; ++p)
#pragma unroll
    for (int b = 0; b < CT; ++b)
      bq[p][b] = *(const half8_t*)(wgp + (size_t)p * CHB + b * 1024);

  for (int m = 0; m < NMAC; ++m) {
#pragma unroll
    for (int j = 0; j < MAC; ++j) {
      constexpr_hint:;
      const int slot = j % 3;            // literal after unroll
      const int cc = m * MAC + j;        // runtime: used only in LDS/global addressing
      int kl;
      if constexpr (MIP == 64) kl = cc >> 1;
      else if constexpr (MIP == 32) kl = cc;
      else kl = 2 * cc + (q >> 1);
#pragma unroll
      for (int s = 0; s < 4; ++s) {
        _Float16 hv = sbuf[(wbase + s * 16 + l15) * HST + kl];
        half8_t af;
        if constexpr (MIP == 64) af = xf[s][j & 1] * hv;   // c0,MAC even -> parity = j&1
        else af = xf[s][0] * hv;
#pragma unroll
        for (int b = 0; b < CT; ++b)
          acc[s][b] = __builtin_amdgcn_mfma_f32_16x16x32_f16(af, bq[slot][b], acc[s][b], 0, 0, 0);
      }
      // prefetch chunk cc+3 into the slot just consumed (clamped address; value unused at tail)
      int cp = cc + 3; if (cp > NCC - 1) cp = NCC - 1;
#pragma unroll
      for (int b = 0; b < CT; ++b)
        bq[slot][b] = *(const half8_t*)(wgp + (size_t)cp * CHB + b * 1024);
    }
  }

  // ---- epilogue: D row = 4q+r (within 16-tile), col = l15; scatter-add ----
#pragma unroll
  for (int s = 0; s < 4; ++s) {
    int rowb = wbase + s * 16 + q * 4;
#pragma unroll
    for (int b = 0; b < CT; ++b) {
      int n = b * 16 + l15;
#pragma unroll
      for (int r = 0; r < 4; ++r) {
        int row = rowb + r;
        if (e0 + row < NE)
          atomicAdd(&xn[(size_t)dsts[row] * MO + n], acc[s][b][r]);
      }
    }
  }
}

// ---- pooling (segment mean over sorted batch, fused ELU) + 3-layer FC head ----
__global__ __launch_bounds__(64) void pool_fc_kernel(
    const float* __restrict__ xn2, const int* __restrict__ batch,
    const float* __restrict__ f1w, const float* __restrict__ f1b,
    const float* __restrict__ f2w, const float* __restrict__ f2b,
    const float* __restrict__ f3w, const float* __restrict__ f3b,
    float* __restrict__ out)
{
  __shared__ float xg[64]; __shared__ float a1[32]; __shared__ float a2[16];
  int g = blockIdx.x, t = threadIdx.x;
  int lo = 0, hi = NN;
  while (lo < hi) { int m = (lo + hi) >> 1; if (batch[m] < g) lo = m + 1; else hi = m; }
  int start = lo; hi = NN;
  while (lo < hi) { int m = (lo + hi) >> 1; if (batch[m] <= g) lo = m + 1; else hi = m; }
  int end = lo;
  float acc = 0.f;
  for (int n = start; n < end; ++n) {
    float v = xn2[(size_t)n * 64 + t];
    acc += v > 0.f ? v : (expf(v) - 1.f);
  }
  float c = (end > start) ? (float)(end - start) : 1.f;
  xg[t] = acc / c;
  __syncthreads();
  if (t < 32) {
    float a = f1b[t];
    for (int i = 0; i < 64; ++i) a = fmaf(xg[i], f1w[i * 32 + t], a);
    a1[t] = a > 0.f ? a : (expf(a) - 1.f);
  }
  __syncthreads();
  if (t < 16) {
    float a = f2b[t];
    for (int i = 0; i < 32; ++i) a = fmaf(a1[i], f2w[i * 16 + t], a);
    a2[t] = a > 0.f ? a : (expf(a) - 1.f);
  }
  __syncthreads();
  if (t == 0) {
    float a = f3b[0];
    for (int i = 0; i < 16; ++i) a = fmaf(a2[i], f3w[i], a);
    out[g] = a;
  }
}

extern "C" void kernel_launch(void* const* d_in, const int* in_sizes, int n_in,
                              void* d_out, int out_size, void* d_ws, size_t ws_size,
                              hipStream_t stream)
{
  const float* x_in  = (const float*)d_in[0];
  const int*   ei    = (const int*)d_in[1];
  const float* ea    = (const float*)d_in[2];
  const int*   batch = (const int*)d_in[3];
  const float* W1[3] = {(const float*)d_in[4],  (const float*)d_in[10], (const float*)d_in[16]};
  const float* B1[3] = {(const float*)d_in[5],  (const float*)d_in[11], (const float*)d_in[17]};
  const float* W2[3] = {(const float*)d_in[6],  (const float*)d_in[12], (const float*)d_in[18]};
  const float* B2[3] = {(const float*)d_in[7],  (const float*)d_in[13], (const float*)d_in[19]};
  const float* RT[3] = {(const float*)d_in[8],  (const float*)d_in[14], (const float*)d_in[20]};
  const float* BS[3] = {(const float*)d_in[9],  (const float*)d_in[15], (const float*)d_in[21]};
  const float* f1w = (const float*)d_in[22]; const float* f1b = (const float*)d_in[23];
  const float* f2w = (const float*)d_in[24]; const float* f2b = (const float*)d_in[25];
  const float* f3w = (const float*)d_in[26]; const float* f3b = (const float*)d_in[27];

  char* ws = (char*)d_ws;
  size_t off = 0;
  auto alloc = [&](size_t bytes) { void* p = ws + off; off += (bytes + 255) & ~(size_t)255; return p; };
  float*    xn0   = (float*)alloc((size_t)NN * 32 * 4);
  float*    xn1   = (float*)alloc((size_t)NN * 64 * 4);
  float*    xn2   = (float*)alloc((size_t)NN * 64 * 4);
  _Float16* e16_0 = (_Float16*)alloc((size_t)NN * 16 * 2);
  _Float16* e16_1 = (_Float16*)alloc((size_t)NN * 32 * 2);
  _Float16* e16_2 = (_Float16*)alloc((size_t)NN * 64 * 2);
  _Float16* w2h0  = (_Float16*)alloc((size_t)72 * 2048);
  _Float16* w2h1  = (_Float16*)alloc((size_t)132 * 4096);
  _Float16* w2h2  = (_Float16*)alloc((size_t)264 * 4096);

  const int* srcp = ei;
  const int* dstp = ei + NE;

  prep_all_kernel<<<(72*2*64 + 132*4*64 + 264*4*64 + 255) / 256, 256, 0, stream>>>(
      W2[0], B2[0], w2h0, W2[1], B2[1], w2h1, W2[2], B2[2], w2h2);
  prep0_kernel<<<NN / 8, 256, 0, stream>>>(x_in, RT[0], BS[0], e16_0, xn0);

  msg6_kernel<16, 32, 18, 36><<<NBLK * NSPLIT, 256, 0, stream>>>(
      ea, W1[0], B1[0], e16_0, srcp, dstp, w2h0, xn0);
  elu_root_kernel<32, 64><<<NN / 4, 256, 0, stream>>>(xn0, RT[1], BS[1], e16_1, xn1);

  msg6_kernel<32, 64, 33, 33><<<NBLK * NSPLIT, 256, 0, stream>>>(
      ea, W1[1], B1[1], e16_1, srcp, dstp, w2h1, xn1);
  elu_root_kernel<64, 64><<<NN / 4, 256, 0, stream>>>(xn1, RT[2], BS[2], e16_2, xn2);

  msg6_kernel<64, 64, 66, 33><<<NBLK * NSPLIT, 256, 0, stream>>>(
      ea, W1[2], B1[2], e16_2, srcp, dstp, w2h2, xn2);

  pool_fc_kernel<<<NG, 64, 0, stream>>>(xn2, batch, f1w, f1b, f2w, f2b, f3w, f3b, (float*)d_out);
}

// Round 7
// 304.999 us; speedup vs baseline: 54.2086x; 1.0287x over previous
//
#include <hip/hip_runtime.h>
#include <stdint.h>
#include <math.h>

typedef _Float16 half8_t __attribute__((ext_vector_type(8)));
typedef float floatx4 __attribute__((ext_vector_type(4)));

#define NN 20000
#define NE 40000
#define NG 1000
#define NBLK 313      // (NE+127)/128
#define NSPLIT 4

// ---- w2(+b2 virtual row) -> fp16 B-fragment chunk images (K padded), all 3 layers ----
__global__ __launch_bounds__(256) void prep_all_kernel(
    const float* __restrict__ w2a, const float* __restrict__ b2a, _Float16* __restrict__ oa,
    const float* __restrict__ w2b, const float* __restrict__ b2b, _Float16* __restrict__ ob,
    const float* __restrict__ w2c, const float* __restrict__ b2c, _Float16* __restrict__ oc)
{
  const int TOT0 = 68 * 2 * 64, TOT1 = 132 * 4 * 64, TOT2 = 264 * 4 * 64;
  int idx = blockIdx.x * 256 + threadIdx.x;
  const float *w2, *b2; _Float16* op; int mi, mo, mpsh, CT;
  if (idx < TOT0) { w2 = w2a; b2 = b2a; op = oa; mi = 13; mo = 32; mpsh = 4; CT = 2; }
  else if (idx < TOT0 + TOT1) { idx -= TOT0; w2 = w2b; b2 = b2b; op = ob; mi = 32; mo = 64; mpsh = 5; CT = 4; }
  else if (idx < TOT0 + TOT1 + TOT2) { idx -= TOT0 + TOT1; w2 = w2c; b2 = b2c; op = oc; mi = 64; mo = 64; mpsh = 6; CT = 4; }
  else return;
  int l = idx & 63;
  int ct = (idx >> 6) % CT;
  int c = idx / (64 * CT);
  int q = l >> 4;
  int n = ct * 16 + (l & 15);
  int mask = (1 << mpsh) - 1;
  half8_t v;
#pragma unroll
  for (int j = 0; j < 8; ++j) {
    int r = c * 32 + q * 8 + j;
    int k = r >> mpsh, i = r & mask;
    float f = 0.f;
    if (i < mi) {
      if (k < 128) f = w2[(size_t)(k * mi + i) * mo + n];
      else if (k == 128) f = b2[(size_t)i * mo + n];
    }
    v[j] = (_Float16)f;
  }
  *(half8_t*)(op + (size_t)idx * 8) = v;
}

// ---- layer-0 prep: x (13) -> e16 padded[16] fp16, and xn0 = x@root0 + bias0 ----
__global__ __launch_bounds__(256) void prep0_kernel(
    const float* __restrict__ x, const float* __restrict__ root,
    const float* __restrict__ bias, _Float16* __restrict__ e16,
    float* __restrict__ xn0)
{
  __shared__ float xs[8 * 13];
  int n0 = blockIdx.x * 8;
  int t = threadIdx.x;
  if (t < 104) xs[t] = x[(size_t)n0 * 13 + t];
  __syncthreads();
  if (t < 128) {
    int r = t >> 4, i = t & 15;
    e16[(size_t)(n0 + r) * 16 + i] = (i < 13) ? (_Float16)xs[r * 13 + i] : (_Float16)0.f;
  }
  int r = t >> 5, o = t & 31;
  float acc = bias[o];
#pragma unroll
  for (int i = 0; i < 13; ++i) acc = fmaf(xs[r * 13 + i], root[i * 32 + o], acc);
  xn0[(size_t)(n0 + r) * 32 + o] = acc;
}

// ---- fused: elu(prev conv out) -> e16 for msg, and xnext = elu(x)@root + bias ----
template <int MI, int MOX>
__global__ __launch_bounds__(256) void elu_root_kernel(
    const float* __restrict__ xin, const float* __restrict__ root,
    const float* __restrict__ bias, _Float16* __restrict__ e16,
    float* __restrict__ xnext)
{
  constexpr int R = 256 / MOX;   // 4 rows/block
  __shared__ float es[R * MI];
  int n0 = blockIdx.x * R;
  int t = threadIdx.x;
  for (int idx = t; idx < R * MI; idx += 256) {
    float v = xin[(size_t)n0 * MI + idx];
    v = v > 0.f ? v : (expf(v) - 1.f);
    es[idx] = v;
    e16[(size_t)n0 * MI + idx] = (_Float16)v;
  }
  __syncthreads();
  int r = t / MOX, o = t % MOX;
  float acc = bias[o];
#pragma unroll 8
  for (int i = 0; i < MI; ++i) acc = fmaf(es[r * MI + i], root[i * MOX + o], acc);
  xnext[(size_t)(n0 + r) * MOX + o] = acc;
}

// ---------------- fused h-MLP + message GEMM + scatter-add ----------------
// C[E,MO] = G[E,Kpad] @ W ; G[e][k*MIP+i] = h[e][k]*x[e][i] (fp16), h[.][128]=1 carries b2.
// Block = 128 edges, 256 thr = 4 waves; wave = M32 x N=MO (8 MFMA/chunk) -> small per-wave
// chunks; grid = 313*4 = 1252 blocks (~4.9 blocks/CU co-resident) for latency hiding via TLP.
// W chunk double-buffered in LDS (1 barrier/chunk); h packed-dup uint rows, odd word stride.
template <int MIP, int MO, int NCC, int KCNT>
__global__ __launch_bounds__(256, 4) void msg7_kernel(
    const float* __restrict__ ea, const float* __restrict__ w1,
    const float* __restrict__ b1, const _Float16* __restrict__ xe,
    const int* __restrict__ src, const int* __restrict__ dst,
    const _Float16* __restrict__ w2h, float* __restrict__ xn)
{
  constexpr int CT = MO / 16;             // 16-col tiles (full N per wave)
  constexpr int CHB = CT * 1024;          // bytes per W chunk image
  constexpr int XLSS = MIP + 8;           // x staging row stride (halves)
  constexpr int HSTW = KCNT | 1;          // h row stride in words (odd -> conflict-free)
  constexpr int XV = (MIP == 64) ? 2 : 1;
  constexpr int NU2 = MIP / 16;           // uint4s per x half-row (thread pair per row)
  constexpr int KH = (KCNT + 1) >> 1;
  constexpr int XB = 128 * XLSS * 2;
  constexpr int HB = 128 * HSTW * 4;
  constexpr int SBYTES = (XB > HB) ? XB : HB;

  __shared__ char sb[SBYTES];             // phase A: x rows (fp16); phase B: h rows (uint)
  __shared__ uint4 wsb[2][CHB / 16];      // double-buffered W chunk
  __shared__ float w1s[5 * 128 + 128];    // w1 then b1
  __shared__ int dsts[128];

  _Float16* sxb = (_Float16*)sb;
  unsigned* hls = (unsigned*)sb;

  const int t = threadIdx.x;
  const int wave = t >> 6, lane = t & 63;
  const int l15 = lane & 15, q = lane >> 4;
  const int split = blockIdx.x / NBLK;
  const int e0 = (blockIdx.x % NBLK) * 128;
  const int c0 = NCC * split;             // even for MIP==64 (NCC=66)
  const int kg0 = KCNT * split;

  // ---- phase A: stage x rows (2 threads/row), w1/b1, dst; edge attrs to regs ----
  {
    int rowA = t >> 1;
    int egA = e0 + rowA; if (egA >= NE) egA = NE - 1;
    const uint4* xr = (const uint4*)(xe + (size_t)src[egA] * MIP);
    uint4* xd = (uint4*)(sxb + rowA * XLSS);
#pragma unroll
    for (int u = 0; u < NU2; ++u) xd[(t & 1) * NU2 + u] = xr[(t & 1) * NU2 + u];
  }
  if (t < 128) {
    int eg = e0 + t; if (eg >= NE) eg = NE - 1;
    dsts[t] = dst[eg];
  }
  const int te = t & 127;
  float ear[5];
  {
    int ege = e0 + te; if (ege >= NE) ege = NE - 1;
#pragma unroll
    for (int j = 0; j < 5; ++j) ear[j] = ea[(size_t)ege * 5 + j];
  }
  for (int i = t; i < 768; i += 256) w1s[i] = (i < 640) ? w1[i] : b1[i - 640];
  __syncthreads();

  // ---- x fragments to registers (2 M-subtiles per wave) ----
  const int wbase = wave * 32;
  half8_t xf[2][XV];
#pragma unroll
  for (int s = 0; s < 2; ++s) {
    int el = wbase + s * 16 + l15;
    int i0 = (MIP == 16) ? (q & 1) * 8 : q * 8;
    xf[s][0] = *(const half8_t*)(sxb + el * XLSS + i0);
    if constexpr (MIP == 64)
      xf[s][XV - 1] = *(const half8_t*)(sxb + el * XLSS + 32 + q * 8);
  }
  __syncthreads();

  // ---- phase B: h rows (packed-dup uint), each edge split across thread halves ----
  {
    int kh = t >> 7;                      // 0/1
    int klo = kh * KH;
    int khi = klo + KH; if (khi > KCNT) khi = KCNT;
    for (int kl = klo; kl < khi; ++kl) {
      int kg = kg0 + kl;
      float v;
      if (kg < 128) {
        v = w1s[640 + kg];
#pragma unroll
        for (int j = 0; j < 5; ++j) v = fmaf(ear[j], w1s[j * 128 + kg], v);
        v = fmaxf(v, 0.f);
      } else v = (kg == 128) ? 1.f : 0.f;
      union { _Float16 f; unsigned short u; } cv; cv.f = (_Float16)v;
      hls[te * HSTW + kl] = (unsigned)cv.u * 0x10001u;
    }
  }
  __syncthreads();

  // ---- K loop: 1 barrier/chunk, double-buffered LDS W, all reg indices static ----
  floatx4 acc[2][CT];
#pragma unroll
  for (int s = 0; s < 2; ++s)
#pragma unroll
    for (int b = 0; b < CT; ++b) acc[s][b] = (floatx4){0.f, 0.f, 0.f, 0.f};

  const char* wgp = (const char*)w2h + (size_t)c0 * CHB;
  uint4 r4; uint2 r2;
  if constexpr (CT == 4) r4 = *(const uint4*)(wgp + t * 16);
  else r2 = *(const uint2*)(wgp + t * 8);

#pragma unroll 2
  for (int cc = 0; cc < NCC; ++cc) {
    if constexpr (CT == 4) wsb[cc & 1][t] = r4;
    else ((uint2*)wsb[cc & 1])[t] = r2;
    __syncthreads();
    if (cc + 1 < NCC) {
      if constexpr (CT == 4) r4 = *(const uint4*)(wgp + (size_t)(cc + 1) * CHB + t * 16);
      else r2 = *(const uint2*)(wgp + (size_t)(cc + 1) * CHB + t * 8);
    }
    const _Float16* wb = (const _Float16*)wsb[cc & 1];
    half8_t bf[CT];
#pragma unroll
    for (int b = 0; b < CT; ++b)
      bf[b] = *(const half8_t*)(wb + (b * 64 + lane) * 8);
    int kl;
    if constexpr (MIP == 64) kl = cc >> 1;
    else if constexpr (MIP == 32) kl = cc;
    else kl = 2 * cc + (q >> 1);
#pragma unroll
    for (int s = 0; s < 2; ++s) {
      _Float16 hv = *(const _Float16*)(hls + (wbase + s * 16 + l15) * HSTW + kl);
      half8_t af;
      if constexpr (MIP == 64) af = xf[s][cc & 1] * hv;   // c0 even -> static parity
      else af = xf[s][0] * hv;
#pragma unroll
      for (int b = 0; b < CT; ++b)
        acc[s][b] = __builtin_amdgcn_mfma_f32_16x16x32_f16(af, bf[b], acc[s][b], 0, 0, 0);
    }
  }

  // ---- epilogue: D row = 4q+r (within 16-tile), col = l15; scatter-add ----
#pragma unroll
  for (int s = 0; s < 2; ++s) {
    int rowb = wbase + s * 16 + q * 4;
#pragma unroll
    for (int b = 0; b < CT; ++b) {
      int n = b * 16 + l15;
#pragma unroll
      for (int r = 0; r < 4; ++r) {
        int row = rowb + r;
        if (e0 + row < NE)
          atomicAdd(&xn[(size_t)dsts[row] * MO + n], acc[s][b][r]);
      }
    }
  }
}

// ---- pooling (segment mean over sorted batch, fused ELU) + 3-layer FC head ----
__global__ __launch_bounds__(64) void pool_fc_kernel(
    const float* __restrict__ xn2, const int* __restrict__ batch,
    const float* __restrict__ f1w, const float* __restrict__ f1b,
    const float* __restrict__ f2w, const float* __restrict__ f2b,
    const float* __restrict__ f3w, const float* __restrict__ f3b,
    float* __restrict__ out)
{
  __shared__ float xg[64]; __shared__ float a1[32]; __shared__ float a2[16];
  int g = blockIdx.x, t = threadIdx.x;
  int lo = 0, hi = NN;
  while (lo < hi) { int m = (lo + hi) >> 1; if (batch[m] < g) lo = m + 1; else hi = m; }
  int start = lo; hi = NN;
  while (lo < hi) { int m = (lo + hi) >> 1; if (batch[m] <= g) lo = m + 1; else hi = m; }
  int end = lo;
  float acc = 0.f;
  for (int n = start; n < end; ++n) {
    float v = xn2[(size_t)n * 64 + t];
    acc += v > 0.f ? v : (expf(v) - 1.f);
  }
  float c = (end > start) ? (float)(end - start) : 1.f;
  xg[t] = acc / c;
  __syncthreads();
  if (t < 32) {
    float a = f1b[t];
    for (int i = 0; i < 64; ++i) a = fmaf(xg[i], f1w[i * 32 + t], a);
    a1[t] = a > 0.f ? a : (expf(a) - 1.f);
  }
  __syncthreads();
  if (t < 16) {
    float a = f2b[t];
    for (int i = 0; i < 32; ++i) a = fmaf(a1[i], f2w[i * 16 + t], a);
    a2[t] = a > 0.f ? a : (expf(a) - 1.f);
  }
  __syncthreads();
  if (t == 0) {
    float a = f3b[0];
    for (int i = 0; i < 16; ++i) a = fmaf(a2[i], f3w[i], a);
    out[g] = a;
  }
}

extern "C" void kernel_launch(void* const* d_in, const int* in_sizes, int n_in,
                              void* d_out, int out_size, void* d_ws, size_t ws_size,
                              hipStream_t stream)
{
  const float* x_in  = (const float*)d_in[0];
  const int*   ei    = (const int*)d_in[1];
  const float* ea    = (const float*)d_in[2];
  const int*   batch = (const int*)d_in[3];
  const float* W1[3] = {(const float*)d_in[4],  (const float*)d_in[10], (const float*)d_in[16]};
  const float* B1[3] = {(const float*)d_in[5],  (const float*)d_in[11], (const float*)d_in[17]};
  const float* W2[3] = {(const float*)d_in[6],  (const float*)d_in[12], (const float*)d_in[18]};
  const float* B2[3] = {(const float*)d_in[7],  (const float*)d_in[13], (const float*)d_in[19]};
  const float* RT[3] = {(const float*)d_in[8],  (const float*)d_in[14], (const float*)d_in[20]};
  const float* BS[3] = {(const float*)d_in[9],  (const float*)d_in[15], (const float*)d_in[21]};
  const float* f1w = (const float*)d_in[22]; const float* f1b = (const float*)d_in[23];
  const float* f2w = (const float*)d_in[24]; const float* f2b = (const float*)d_in[25];
  const float* f3w = (const float*)d_in[26]; const float* f3b = (const float*)d_in[27];

  char* ws = (char*)d_ws;
  size_t off = 0;
  auto alloc = [&](size_t bytes) { void* p = ws + off; off += (bytes + 255) & ~(size_t)255; return p; };
  float*    xn0   = (float*)alloc((size_t)NN * 32 * 4);
  float*    xn1   = (float*)alloc((size_t)NN * 64 * 4);
  float*    xn2   = (float*)alloc((size_t)NN * 64 * 4);
  _Float16* e16_0 = (_Float16*)alloc((size_t)NN * 16 * 2);
  _Float16* e16_1 = (_Float16*)alloc((size_t)NN * 32 * 2);
  _Float16* e16_2 = (_Float16*)alloc((size_t)NN * 64 * 2);
  _Float16* w2h0  = (_Float16*)alloc((size_t)68 * 2048);
  _Float16* w2h1  = (_Float16*)alloc((size_t)132 * 4096);
  _Float16* w2h2  = (_Float16*)alloc((size_t)264 * 4096);

  const int* srcp = ei;
  const int* dstp = ei + NE;

  prep_all_kernel<<<(68*2*64 + 132*4*64 + 264*4*64 + 255) / 256, 256, 0, stream>>>(
      W2[0], B2[0], w2h0, W2[1], B2[1], w2h1, W2[2], B2[2], w2h2);
  prep0_kernel<<<NN / 8, 256, 0, stream>>>(x_in, RT[0], BS[0], e16_0, xn0);

  msg7_kernel<16, 32, 17, 34><<<NBLK * NSPLIT, 256, 0, stream>>>(
      ea, W1[0], B1[0], e16_0, srcp, dstp, w2h0, xn0);
  elu_root_kernel<32, 64><<<NN / 4, 256, 0, stream>>>(xn0, RT[1], BS[1], e16_1, xn1);

  msg7_kernel<32, 64, 33, 33><<<NBLK * NSPLIT, 256, 0, stream>>>(
      ea, W1[1], B1[1], e16_1, srcp, dstp, w2h1, xn1);
  elu_root_kernel<64, 64><<<NN / 4, 256, 0, stream>>>(xn1, RT[2], BS[2], e16_2, xn2);

  msg7_kernel<64, 64, 66, 33><<<NBLK * NSPLIT, 256, 0, stream>>>(
      ea, W1[2], B1[2], e16_2, srcp, dstp, w2h2, xn2);

  pool_fc_kernel<<<NG, 64, 0, stream>>>(xn2, batch, f1w, f1b, f2w, f2b, f3w, f3b, (float*)d_out);
}